// Round 5
// baseline (452.012 us; speedup 1.0000x reference)
//
#include <hip/hip_runtime.h>
#include <math.h>

#define PI_D 3.141592653589793238462643383279502884

typedef __attribute__((ext_vector_type(8))) short short8;
typedef __attribute__((ext_vector_type(4))) float f32x4;

// ---- ws layout (float units) ----
#define WS_SP    0            // 256*4096 spatial images
#define WS_GR    1048576      // 1024 blocks * 3840 floats gram partials
#define WS_MS    4980736      // 256*48 per-channel sums (atomic)
#define WS_SCAL  4993024      // 256*4 (tsum,tsq,dsq) (atomic)
#define WS_ETEX  4994048      // 256 etex accumulators (atomic)
#define WS_TOTAL 4994304

__device__ __forceinline__ float wr_sum(float v) {
#pragma unroll
  for (int o = 32; o; o >>= 1) v += __shfl_xor(v, o, 64);
  return v;
}
__device__ __forceinline__ float wr_min(float v) {
#pragma unroll
  for (int o = 32; o; o >>= 1) v = fminf(v, __shfl_xor(v, o, 64));
  return v;
}
__device__ __forceinline__ float wr_max(float v) {
#pragma unroll
  for (int o = 32; o; o >>= 1) v = fmaxf(v, __shfl_xor(v, o, 64));
  return v;
}
__device__ float block_reduce(float v, float* red) {
  v = wr_sum(v);
  __syncthreads();
  if ((threadIdx.x & 63) == 0) red[threadIdx.x >> 6] = v;
  __syncthreads();
  return red[0] + red[1] + red[2] + red[3];
}

__device__ __forceinline__ unsigned int bf16rne(float f) {
  unsigned int u = __float_as_uint(f);
  return (u + 0x7fffu + ((u >> 16) & 1u)) >> 16;
}
__device__ __forceinline__ unsigned int packhl(float f) {
  unsigned int hb = bf16rne(f);
  float hf = __uint_as_float(hb << 16);
  unsigned int lb = bf16rne(f - hf);
  return (hb & 0xffffu) | (lb << 16);
}

#define MF(a, b, c) __builtin_amdgcn_mfma_f32_16x16x32_bf16(a, b, c, 0, 0, 0)

__device__ __forceinline__ void loadch(const float* __restrict__ xb, int px0,
                                       int tid, float4* dst) {
#pragma unroll
  for (int it = 0; it < 5; ++it) {
    int idx = it * 256 + tid;
    if (idx < 1088) {
      int c = idx >> 5, p4 = idx & 31;
      dst[it] = *(const float4*)(xb + c * 4096 + px0 + p4 * 4);
    }
  }
}

// =======================================================================
// Kernel A: stream x once. grid = 256 batches x 4 slabs (1024 px each).
// LDS ~25.8 KB (gram merge buffer ALIASED onto the staging tile) so all
// 1024 blocks are co-resident (4 blocks/CU) -> no dispatch tail.
// =======================================================================
__global__ void __launch_bounds__(256, 4)
mfeA(const float* __restrict__ x, float* __restrict__ ws) {
  const int bid = blockIdx.x;
  const int b = bid >> 2;
  const int slab = bid & 3;
  const int tid = threadIdx.x;
  const int lane = tid & 63, wv = tid >> 6;
  const float* xb = x + (size_t)b * (34 * 4096);
  const int px_base = slab * 1024;

  __shared__ unsigned int tile[48 * 134];  // interleaved h|l<<16, stride 134
  __shared__ float red[4];

  float4 cur[5], nxt[5];
  loadch(xb, px_base, tid, cur);           // prefetch chunk 0 ASAP

  // zero-pad channels 34..47 (never overwritten)
  for (int i = 34 * 134 + tid; i < 48 * 134; i += 256) tile[i] = 0u;

  f32x4 acc[15];
#pragma unroll
  for (int t = 0; t < 15; ++t) acc[t] = (f32x4){0.f, 0.f, 0.f, 0.f};
  float msl[17];
#pragma unroll
  for (int i = 0; i < 17; ++i) msl[i] = 0.f;
  float tsum = 0.f, tsq = 0.f, dsq = 0.f;

  const int half = lane >> 5, pxi = lane & 31;
  const int wpx = wv * 32;
  const int c0s = half * 17;

#pragma unroll 1
  for (int cj = 0; cj < 8; ++cj) {
    const int px0 = px_base + cj * 128;
    // ---- convert regs (loaded last iter) -> LDS; exact f32 stats ----
#pragma unroll
    for (int it = 0; it < 5; ++it) {
      int idx = it * 256 + tid;
      if (idx < 1088) {
        const float4 v = cur[it];
        tsum += v.x + v.y + v.z + v.w;
        tsq += v.x * v.x + v.y * v.y + v.z * v.z + v.w * v.w;
        int c = idx >> 5, p4 = idx & 31;
        unsigned int base = c * 134 + p4 * 4;
        uint2 w0, w1;
        w0.x = packhl(v.x); w0.y = packhl(v.y);
        w1.x = packhl(v.z); w1.y = packhl(v.w);
        *(uint2*)&tile[base] = w0;
        *(uint2*)&tile[base + 2] = w1;
      }
    }
    __syncthreads();
    // ---- issue next chunk's loads (latency hides under compute) ----
    if (cj < 7) loadch(xb, px0 + 128, tid, nxt);
    // ---- Gram: this wave's 32-px k-step ----
    {
      short8 Ah[3], Al[3];
#pragma unroll
      for (int ct = 0; ct < 3; ++ct) {
        int c = ct * 16 + (lane & 15);
        int iu = c * 134 + wpx + (lane >> 4) * 8;
        uint2 q0 = *(const uint2*)&tile[iu + 0];
        uint2 q1 = *(const uint2*)&tile[iu + 2];
        uint2 q2 = *(const uint2*)&tile[iu + 4];
        uint2 q3 = *(const uint2*)&tile[iu + 6];
        short8 h, l;
        h[0] = (short)(q0.x & 0xffffu); l[0] = (short)(q0.x >> 16);
        h[1] = (short)(q0.y & 0xffffu); l[1] = (short)(q0.y >> 16);
        h[2] = (short)(q1.x & 0xffffu); l[2] = (short)(q1.x >> 16);
        h[3] = (short)(q1.y & 0xffffu); l[3] = (short)(q1.y >> 16);
        h[4] = (short)(q2.x & 0xffffu); l[4] = (short)(q2.x >> 16);
        h[5] = (short)(q2.y & 0xffffu); l[5] = (short)(q2.y >> 16);
        h[6] = (short)(q3.x & 0xffffu); l[6] = (short)(q3.x >> 16);
        h[7] = (short)(q3.y & 0xffffu); l[7] = (short)(q3.y >> 16);
        Ah[ct] = h; Al[ct] = l;
      }
      acc[0] = MF(Ah[0], Ah[0], acc[0]);
      acc[1] = MF(Ah[0], Ah[1], acc[1]);
      acc[2] = MF(Ah[0], Ah[2], acc[2]);
      acc[3] = MF(Ah[1], Ah[1], acc[3]);
      acc[4] = MF(Ah[1], Ah[2], acc[4]);
      acc[5] = MF(Ah[2], Ah[2], acc[5]);
      acc[6]  = MF(Ah[0], Al[0], acc[6]);
      acc[7]  = MF(Ah[0], Al[1], acc[7]);
      acc[8]  = MF(Ah[0], Al[2], acc[8]);
      acc[9]  = MF(Ah[1], Al[0], acc[9]);
      acc[10] = MF(Ah[1], Al[1], acc[10]);
      acc[11] = MF(Ah[1], Al[2], acc[11]);
      acc[12] = MF(Ah[2], Al[0], acc[12]);
      acc[13] = MF(Ah[2], Al[1], acc[13]);
      acc[14] = MF(Ah[2], Al[2], acc[14]);
    }
    // ---- stats from LDS: (wave, half) owns 17 channels x 32 px ----
    {
      float colsum = 0.f, prev = 0.f;
      if (half) {
        unsigned int u = tile[16 * 134 + wpx + pxi];
        prev = __uint_as_float(u << 16) + __uint_as_float(u & 0xffff0000u);
      }
#pragma unroll
      for (int i = 0; i < 17; ++i) {
        unsigned int u = tile[(c0s + i) * 134 + wpx + pxi];
        float v = __uint_as_float(u << 16) + __uint_as_float(u & 0xffff0000u);
        colsum += v; msl[i] += v;
        if (half || i) { float d = v - prev; dsq += d * d; }
        prev = v;
      }
      float tot = colsum + __shfl_xor(colsum, 32, 64);
      if (!half) ws[WS_SP + b * 4096 + px0 + wpx + pxi] = tot * (1.f / 34.f);
    }
    __syncthreads();
    if (cj < 7) {
#pragma unroll
      for (int it = 0; it < 5; ++it) cur[it] = nxt[it];
    }
  }

  // ---- per-channel sums: butterfly across 32 px lanes ----
#pragma unroll
  for (int i = 0; i < 17; ++i) {
    float s = msl[i];
    s += __shfl_xor(s, 1, 64); s += __shfl_xor(s, 2, 64);
    s += __shfl_xor(s, 4, 64); s += __shfl_xor(s, 8, 64);
    s += __shfl_xor(s, 16, 64);
    msl[i] = s;
  }
  if (pxi < 17) {
    float v = 0.f;
#pragma unroll
    for (int i = 0; i < 17; ++i) if (pxi == i) v = msl[i];
    atomicAdd(ws + WS_MS + b * 48 + c0s + pxi, v);
  }

  // ---- scalar stats (atomic, tiny) ----
  float T1 = block_reduce(tsum, red);
  float T2 = block_reduce(tsq, red);
  float T3 = block_reduce(dsq, red);
  if (tid == 0) {
    atomicAdd(ws + WS_SCAL + b * 4 + 0, T1);
    atomicAdd(ws + WS_SCAL + b * 4 + 1, T2);
    atomicAdd(ws + WS_SCAL + b * 4 + 2, T3);
  }

  // ---- Gram: cross-wave merge in LDS (ALIASED onto tile), then store ----
  // Last tile read was before the loop-final __syncthreads(); block_reduce
  // barriers above keep everything ordered.
  float* gmerge = (float*)tile;   // needs 3840 floats <= 6432 available
  for (int i = tid; i < 3840; i += 256) gmerge[i] = 0.f;
  __syncthreads();
#pragma unroll
  for (int t = 0; t < 15; ++t)
#pragma unroll
    for (int r = 0; r < 4; ++r)
      atomicAdd(&gmerge[t * 256 + lane * 4 + r], acc[t][r]);
  __syncthreads();
  {
    float* grbase = ws + WS_GR + (size_t)bid * 3840;
    for (int i = tid; i < 960; i += 256)
      *(float4*)(grbase + i * 4) = *(const float4*)&gmerge[i * 4];
  }
}

// =======================================================================
// Kernel B helpers
// =======================================================================
template<int R>
__device__ void hpass(const float* __restrict__ src, float* __restrict__ dst,
                      const float* __restrict__ pf, int tid) {
  const int row = tid >> 2, c0 = (tid & 3) << 4;
  float pr[2 * R + 1];
#pragma unroll
  for (int t = 0; t < 2 * R + 1; ++t) pr[t] = pf[t];
  float w[16 + 2 * R];
#pragma unroll
  for (int k = 0; k < 16 + 2 * R; ++k) {
    int cc = c0 - R + k;
    w[k] = (cc >= 0 && cc < 64) ? src[row * 65 + cc] : 0.f;
  }
#pragma unroll
  for (int o = 0; o < 16; ++o) {
    float a = 0.f;
#pragma unroll
    for (int t = 0; t < 2 * R + 1; ++t) a += pr[t] * w[o + t];
    dst[row * 65 + c0 + o] = a;
  }
}
template<int R>
__device__ void vpass1(const float* __restrict__ H, const float* __restrict__ pf,
                       int tid, float& s1, float& s2) {
  const int c = tid & 63, r0 = (tid >> 6) << 4;
  float pr[2 * R + 1];
#pragma unroll
  for (int t = 0; t < 2 * R + 1; ++t) pr[t] = pf[t];
  float w[16 + 2 * R];
#pragma unroll
  for (int k = 0; k < 16 + 2 * R; ++k) {
    int rr = r0 - R + k;
    w[k] = (rr >= 0 && rr < 64) ? H[rr * 65 + c] : 0.f;
  }
#pragma unroll
  for (int o = 0; o < 16; ++o) {
    float y = 0.f;
#pragma unroll
    for (int t = 0; t < 2 * R + 1; ++t) y += pr[t] * w[o + t];
    s1 += y; s2 += y * y;
  }
}

__device__ __forceinline__ void emit(float* out, int b, int f, float v) {
  v = fminf(fmaxf(v, 0.f), 1.f);
  out[b * 12 + f] = 1.f / (1.f + expf(-v));
}

// =======================================================================
// Kernel B: grid (256 batches, 20 types).
// type 0: gram reduce + ms/corr/scalar -> feats 1,2,4,5,6,9,11
// type 1: boxcount + contrast          -> feats 0,3
// type 2: LBP                          -> feat 10
// type 3: Sobel                        -> feat 8
// types 4-19: ONE gabor component each -> atomicAdd etex acc
//   comp = type-4; sf = comp>>2; u = comp&3 (0:th0 1:th90 2:cc 3:ss)
//   var(th45)+var(th135) == 2var(cc)+2var(ss)  [cov term cancels]
// =======================================================================
__global__ void __launch_bounds__(256)
mfeB(const float* __restrict__ ws, float* __restrict__ out) {
  const int b = blockIdx.x;
  const int type = blockIdx.y;
  const int tid = threadIdx.x;

  __shared__ float sm[2 * 64 * 65];   // sp | H1 (33.3 KB -> 4 blocks/CU)
  __shared__ float prof[40];
  __shared__ float red[4];
  __shared__ int icnt[5];
  __shared__ float sA[48];
  __shared__ float sB[48];

  float* sp = sm;

  if (type == 0) {
    // ------------- gram slab reduce -> LDS, then corr etc -------------
    float* hhL = sm;            // 48x48
    float* hlL = sm + 2304;     // 48x48
    const int TI[15] = {0,0,0,1,1,2, 0,0,0,1,1,1,2,2,2};
    const int TJ[15] = {0,1,2,1,2,2, 0,1,2,0,1,2,0,1,2};
    {
      const float* g0 = ws + WS_GR + (size_t)(b * 4 + 0) * 3840;
      const float* g1 = ws + WS_GR + (size_t)(b * 4 + 1) * 3840;
      const float* g2 = ws + WS_GR + (size_t)(b * 4 + 2) * 3840;
      const float* g3 = ws + WS_GR + (size_t)(b * 4 + 3) * 3840;
      for (int fi = tid; fi < 960; fi += 256) {
        float4 v0 = *(const float4*)(g0 + fi * 4);
        float4 v1 = *(const float4*)(g1 + fi * 4);
        float4 v2 = *(const float4*)(g2 + fi * 4);
        float4 v3 = *(const float4*)(g3 + fi * 4);
        float s0 = v0.x + v1.x + v2.x + v3.x;
        float s1 = v0.y + v1.y + v2.y + v3.y;
        float s2 = v0.z + v1.z + v2.z + v3.z;
        float s3 = v0.w + v1.w + v2.w + v3.w;
        int t = fi >> 6, l = fi & 63;
        int row0 = TI[t] * 16 + (l >> 4) * 4;
        int col = TJ[t] * 16 + (l & 15);
        float* dst = (t < 6) ? hhL : hlL;
        dst[(row0 + 0) * 48 + col] = s0;
        dst[(row0 + 1) * 48 + col] = s1;
        dst[(row0 + 2) * 48 + col] = s2;
        dst[(row0 + 3) * 48 + col] = s3;
      }
    }
    if (tid < 34) sA[tid] = ws[WS_MS + b * 48 + tid] * (1.f / 4096.f);
    __syncthreads();
    if (tid < 34) {
      float m = sA[tid];
      float cii = hhL[tid * 48 + tid] + 2.f * hlL[tid * 48 + tid] - 4096.f * m * m;
      sB[tid] = sqrtf(fmaxf(cii, 0.f));
    }
    __syncthreads();
    float cs = 0.f;
    for (int idx = tid; idx < 1156; idx += 256) {
      int i = idx / 34, j = idx - (idx / 34) * 34;
      float hh = ((i >> 4) <= (j >> 4)) ? hhL[i * 48 + j] : hhL[j * 48 + i];
      float cov = hh + hlL[i * 48 + j] + hlL[j * 48 + i] - 4096.f * sA[i] * sA[j];
      cs += cov / (sB[i] * sB[j]);
    }
    float CS = block_reduce(cs, red);

    if (tid < 64) {
      bool act = tid < 34;
      float mi = act ? sA[tid] : 3.4e38f;
      float mn = wr_min(mi);
      float mx = wr_max(act ? sA[tid] : -3.4e38f);
      float v = act ? (sA[tid] - mn) : 0.f;
      float vs = wr_sum(v);
      float pp = v / (vs + 1e-8f);
      float ent = act ? pp * log2f(pp + 1e-8f) : 0.f;
      float es = wr_sum(ent);
      float fi = act ? -sA[tid] : 0.f;
      float prom = 0.f; bool valid = false;
      if (act) {
        int i = tid, lb = -1, rb = 34;
        for (int j = 0; j < 34; ++j) {
          float fj = -sA[j];
          if (fj > fi) { if (j < i && j > lb) lb = j; if (j > i && j < rb) rb = j; }
        }
        float lmin = 3.4e38f, rmin = 3.4e38f;
        for (int j = lb + 1; j < i; ++j) lmin = fminf(lmin, -sA[j]);
        for (int j = i + 1; j < rb; ++j) rmin = fminf(rmin, -sA[j]);
        prom = fi - fmaxf(lmin, rmin);
        bool ispk = (i > 0) && (i < 33) && (fi > -sA[i - 1]) && (fi > -sA[i + 1]);
        valid = ispk && (prom >= 0.05f);
      }
      float cnt = wr_sum(valid ? 1.f : 0.f);
      float tot = wr_sum(valid ? prom : 0.f);
      if (tid == 0) {
        float T1 = ws[WS_SCAL + b * 4 + 0];
        float T2 = ws[WS_SCAL + b * 4 + 1];
        float T3 = ws[WS_SCAL + b * 4 + 2];
        const float NA = 34.f * 4096.f;
        float mu = T1 / NA;
        float sd = sqrtf(fmaxf(T2 / NA - mu * mu, 0.f));
        float snr = fminf(fmaxf(20.f * log10f(mu / (sd + 1e-8f)), 0.f), 50.f) * (1.f / 50.f);
        const float ND = 33.f * 4096.f;
        float md = (ws[WS_MS + b * 48 + 33] - ws[WS_MS + b * 48 + 0]) / ND;
        emit(out, b, 1, T3 / ND - md * md);                       // sgv
        emit(out, b, 2, snr);                                     // snr
        emit(out, b, 4, -es / (float)5.087462841250339);          // hl
        emit(out, b, 5, mu);                                      // mu
        emit(out, b, 6, (CS - 34.f) / (34.f * 33.f));             // avg_corr
        emit(out, b, 9, mx - mn);                                 // sc
        emit(out, b, 11, (cnt > 0.f) ? tot / cnt : 0.f);          // ad
      }
    }
    return;
  }

  // all other types need the spatial image in LDS (stride 65)
  for (int i = tid; i < 1024; i += 256) {
    float4 v = *(const float4*)(ws + WS_SP + b * 4096 + i * 4);
    int r = i >> 4, c = (i & 15) * 4;
    float* d = &sp[r * 65 + c];
    d[0] = v.x; d[1] = v.y; d[2] = v.z; d[3] = v.w;
  }
  if (type == 1 && tid < 5) icnt[tid] = 0;
  if (type >= 4) {
    const int comp = type - 4;
    const int sf = comp >> 2, u = comp & 3;
    if (tid < 38) {
      int uu = tid / 19, t = tid % 19;   // uu: 0=h profile, 1=v profile
      double sg = (sf >= 2) ? 3.0 : 1.0;
      double fr = (sf & 1) ? 0.3 : 0.1;
      int R = (u < 2) ? ((sf >= 2) ? 9 : 3) : ((sf >= 2) ? 7 : 3);
      float val = 0.f;
      if (t <= 2 * R) {
        double d = (double)(t - R);
        double E = exp(-0.5 * d * d / (sg * sg));
        double nrm = 1.0 / (2.0 * PI_D * sg * sg);
        double w = 2.0 * PI_D * fr;
        double a = w * sqrt(0.5);
        double v = 0.0;
        if (u == 0)      v = uu ? (E * nrm) : (E * cos(w * d));
        else if (u == 1) v = uu ? (E * cos(w * d) * nrm) : E;
        else if (u == 2) v = uu ? (E * cos(a * d) * nrm) : (E * cos(a * d));
        else             v = uu ? (E * sin(a * d) * nrm) : (E * sin(a * d));
        val = (float)v;
      }
      prof[uu * 19 + t] = val;
    }
  }
  __syncthreads();

  if (type == 1) {
    // ------------- boxcount pyramid + contrast -------------
    float* Amx = sm + 4160;
    float* Amn = Amx + 1056;
    float* Bmx = Amx + 2112;
    float* Bmn = Amx + 2384;
    {
      int c2 = 0;
#pragma unroll
      for (int it = 0; it < 4; ++it) {
        int idx = it * 256 + tid;
        int br = idx >> 5, bc = idx & 31;
        int r = br * 2, c = bc * 2;
        float q00 = floorf(sp[r * 65 + c] * 255.f);
        float q01 = floorf(sp[r * 65 + c + 1] * 255.f);
        float q10 = floorf(sp[(r + 1) * 65 + c] * 255.f);
        float q11 = floorf(sp[(r + 1) * 65 + c + 1] * 255.f);
        float mxv = fmaxf(fmaxf(q00, q01), fmaxf(q10, q11));
        float mnv = fminf(fminf(q00, q01), fminf(q10, q11));
        Amx[br * 33 + bc] = mxv; Amn[br * 33 + bc] = mnv;
        if (mxv > mnv) ++c2;
      }
      atomicAdd(&icnt[0], c2);
    }
    __syncthreads();
    {
      int br = tid >> 4, bc = tid & 15;
      int i0 = (br * 2) * 33 + bc * 2;
      float mxv = fmaxf(fmaxf(Amx[i0], Amx[i0 + 1]), fmaxf(Amx[i0 + 33], Amx[i0 + 34]));
      float mnv = fminf(fminf(Amn[i0], Amn[i0 + 1]), fminf(Amn[i0 + 33], Amn[i0 + 34]));
      Bmx[br * 17 + bc] = mxv; Bmn[br * 17 + bc] = mnv;
      if (mxv > mnv) atomicAdd(&icnt[1], 1);
    }
    __syncthreads();
    if (tid < 64) {
      int br = tid >> 3, bc = tid & 7;
      int i0 = (br * 2) * 17 + bc * 2;
      float mxv = fmaxf(fmaxf(Bmx[i0], Bmx[i0 + 1]), fmaxf(Bmx[i0 + 17], Bmx[i0 + 18]));
      float mnv = fminf(fminf(Bmn[i0], Bmn[i0 + 1]), fminf(Bmn[i0 + 17], Bmn[i0 + 18]));
      Amx[br * 9 + bc] = mxv; Amn[br * 9 + bc] = mnv;
      if (mxv > mnv) atomicAdd(&icnt[2], 1);
    }
    __syncthreads();
    if (tid < 16) {
      int br = tid >> 2, bc = tid & 3;
      int i0 = (br * 2) * 9 + bc * 2;
      float mxv = fmaxf(fmaxf(Amx[i0], Amx[i0 + 1]), fmaxf(Amx[i0 + 9], Amx[i0 + 10]));
      float mnv = fminf(fminf(Amn[i0], Amn[i0 + 1]), fminf(Amn[i0 + 9], Amn[i0 + 10]));
      Bmx[br * 5 + bc] = mxv; Bmn[br * 5 + bc] = mnv;
      if (mxv > mnv) atomicAdd(&icnt[3], 1);
    }
    __syncthreads();
    if (tid < 4) {
      int br = tid >> 1, bc = tid & 1;
      int i0 = (br * 2) * 5 + bc * 2;
      float mxv = fmaxf(fmaxf(Bmx[i0], Bmx[i0 + 1]), fmaxf(Bmx[i0 + 5], Bmx[i0 + 6]));
      float mnv = fminf(fminf(Bmn[i0], Bmn[i0 + 1]), fminf(Bmn[i0 + 5], Bmn[i0 + 6]));
      if (mxv > mnv) atomicAdd(&icnt[4], 1);
    }
    float contr = 0.f;
#pragma unroll 4
    for (int k = 0; k < 16; ++k) {
      int p = k * 256 + tid;
      int r = p >> 6, c = p & 63;
      if (c < 63) {
        float d = floorf(sp[r * 65 + c] * 255.f) - floorf(sp[r * 65 + c + 1] * 255.f);
        contr += d * d;
      }
    }
    float CTt = block_reduce(contr, red);
    if (tid == 0) {
      float cm = CTt * (1.f / 4032.f);
      emit(out, b, 3, 1.f / (1.f + cm * 0.01f));   // hs
      float lxv[5] = {logf(2.f), logf(4.f), logf(8.f), logf(16.f), logf(32.f)};
      float lxm = (lxv[0] + lxv[1] + lxv[2] + lxv[3] + lxv[4]) * 0.2f;
      float num = 0.f, den = 0.f;
#pragma unroll
      for (int i = 0; i < 5; ++i) {
        float cntf = fmaxf((float)icnt[i], 1.f);
        float lc = lxv[i] - lxm;
        num += logf(cntf) * lc;
        den += lc * lc;
      }
      emit(out, b, 0, fminf(fmaxf(-(num / den), 1.f), 2.f));   // df
    }
  } else if (type == 2) {
    // ------------- LBP variance -------------
    const double Sd = sqrt(0.5);
    const float W_A = (float)(Sd * (1.0 - Sd));
    const float W_B = (float)(Sd * Sd);
    const float W_C = (float)((1.0 - Sd) * (1.0 - Sd));
    float ls = 0.f, ls2 = 0.f;
#pragma unroll 4
    for (int k = 0; k < 16; ++k) {
      int p = k * 256 + tid;
      int r = p >> 6, c = p & 63;
      float n[3][3];
#pragma unroll
      for (int i = 0; i < 3; ++i)
#pragma unroll
        for (int j = 0; j < 3; ++j) {
          int rr = r + i - 1, cc = c + j - 1;
          n[i][j] = (rr >= 0 && rr < 64 && cc >= 0 && cc < 64) ? sp[rr * 65 + cc] : 0.f;
        }
      float ctr = n[1][1];
      float v1 = W_A * n[0][1] + W_B * n[0][2] + W_C * n[1][1] + W_A * n[1][2];
      float v3 = W_B * n[0][0] + W_A * n[0][1] + W_A * n[1][0] + W_C * n[1][1];
      float v5 = W_A * n[1][0] + W_C * n[1][1] + W_B * n[2][0] + W_A * n[2][1];
      float v7 = W_C * n[1][1] + W_A * n[1][2] + W_A * n[2][1] + W_B * n[2][2];
      bool bt[8];
      bt[0] = n[1][2] >= ctr; bt[1] = v1 >= ctr; bt[2] = n[0][1] >= ctr; bt[3] = v3 >= ctr;
      bt[4] = n[1][0] >= ctr; bt[5] = v5 >= ctr; bt[6] = n[2][1] >= ctr; bt[7] = v7 >= ctr;
      int ones = 0, trans = 0;
#pragma unroll
      for (int q = 0; q < 8; ++q) { ones += bt[q] ? 1 : 0; trans += (bt[q] != bt[(q + 1) & 7]) ? 1 : 0; }
      float lbp = (trans <= 2) ? (float)ones : 9.f;
      ls += lbp; ls2 += lbp * lbp;
    }
    float S1 = block_reduce(ls, red), S2 = block_reduce(ls2, red);
    if (tid == 0) {
      float m = S1 * (1.f / 4096.f);
      emit(out, b, 10, fminf(1.f, (S2 * (1.f / 4096.f) - m * m) * 0.01f));  // lbpv
    }
  } else if (type == 3) {
    // ------------- Sobel edge fraction -------------
    int ec = 0;
#pragma unroll 4
    for (int k = 0; k < 16; ++k) {
      int p = k * 256 + tid;
      int r = p >> 6, c = p & 63;
      float P[3][3];
#pragma unroll
      for (int i = 0; i < 3; ++i)
#pragma unroll
        for (int j = 0; j < 3; ++j) {
          int rr = min(max(r + i - 1, 0), 63);
          int cc = min(max(c + j - 1, 0), 63);
          P[i][j] = sp[rr * 65 + cc];
        }
      float gx = (P[0][2] - P[0][0]) + 2.f * (P[1][2] - P[1][0]) + (P[2][2] - P[2][0]);
      float gy = (P[2][0] - P[0][0]) + 2.f * (P[2][1] - P[0][1]) + (P[2][2] - P[0][2]);
      if (gx * gx + gy * gy > 0.01f) ++ec;
    }
    float E = block_reduce((float)ec, red);
    if (tid == 0) emit(out, b, 8, E * (1.f / 4096.f));  // edge
  } else {
    // ------------- Gabor: ONE separable component per block -------------
    const int comp = type - 4;
    const int sf = comp >> 2, u = comp & 3;
    float* H1 = sm + 4160;
    float s1 = 0.f, s2 = 0.f;
    if (sf < 2) {
      hpass<3>(sp, H1, prof, tid); __syncthreads();
      vpass1<3>(H1, prof + 19, tid, s1, s2);
    } else if (u < 2) {
      hpass<9>(sp, H1, prof, tid); __syncthreads();
      vpass1<9>(H1, prof + 19, tid, s1, s2);
    } else {
      hpass<7>(sp, H1, prof, tid); __syncthreads();
      vpass1<7>(H1, prof + 19, tid, s1, s2);
    }
    float S1 = block_reduce(s1, red), S2 = block_reduce(s2, red);
    if (tid == 0) {
      const float inv = 1.f / 4096.f;
      float var = S2 * inv - (S1 * inv) * (S1 * inv);
      float wgt = (u < 2) ? 1.f : 2.f;   // diag pair: var sum = 2var(cc)+2var(ss)
      atomicAdd((float*)(ws + WS_ETEX + b), wgt * var * (1.f / 1600.f));
    }
  }
}

// =======================================================================
// Kernel C: finalize etex (feat 7) after all gabor blocks accumulated.
// =======================================================================
__global__ void __launch_bounds__(256)
mfeC(const float* __restrict__ ws, float* __restrict__ out) {
  int b = threadIdx.x;
  emit(out, b, 7, ws[WS_ETEX + b]);
}

extern "C" void kernel_launch(void* const* d_in, const int* in_sizes, int n_in,
                              void* d_out, int out_size, void* d_ws, size_t ws_size,
                              hipStream_t stream) {
  (void)in_sizes; (void)n_in; (void)out_size;
  // Needs ~20 MB scratch; bail cleanly (clean failed-verify) if undersized.
  if (ws_size < (size_t)WS_TOTAL * sizeof(float)) return;
  const float* x = (const float*)d_in[0];
  float* out = (float*)d_out;
  float* ws = (float*)d_ws;
  // zero only the atomic-accumulated regions (MS, SCAL, ETEX) — 54 KB
  hipMemsetAsync((char*)d_ws + (size_t)WS_MS * 4, 0,
                 (size_t)(WS_TOTAL - WS_MS) * 4, stream);
  hipLaunchKernelGGL(mfeA, dim3(1024), dim3(256), 0, stream, x, ws);
  hipLaunchKernelGGL(mfeB, dim3(256, 20), dim3(256), 0, stream, ws, out);
  hipLaunchKernelGGL(mfeC, dim3(1), dim3(256), 0, stream, ws, out);
}

// Round 6
// 322.346 us; speedup vs baseline: 1.4023x; 1.4023x over previous
//
#include <hip/hip_runtime.h>
#include <math.h>

#define PI_D 3.141592653589793238462643383279502884

typedef __attribute__((ext_vector_type(8))) short short8;
typedef __attribute__((ext_vector_type(4))) float f32x4;

// ---- ws layout (float units) ----
#define WS_SP    0            // 256*4096 spatial images
#define WS_GR    1048576      // 1024 blocks * 3840 floats gram partials
#define WS_MS    4980736      // 256*48 per-channel sums (atomic)
#define WS_SCAL  4993024      // 256*4 (tsum,tsq,dsq) (atomic)
#define WS_ETEX  4994048      // 256 etex accumulators (atomic)
#define WS_TOTAL 4994304

__device__ __forceinline__ float wr_sum(float v) {
#pragma unroll
  for (int o = 32; o; o >>= 1) v += __shfl_xor(v, o, 64);
  return v;
}
__device__ __forceinline__ float wr_min(float v) {
#pragma unroll
  for (int o = 32; o; o >>= 1) v = fminf(v, __shfl_xor(v, o, 64));
  return v;
}
__device__ __forceinline__ float wr_max(float v) {
#pragma unroll
  for (int o = 32; o; o >>= 1) v = fmaxf(v, __shfl_xor(v, o, 64));
  return v;
}
__device__ float block_reduce(float v, float* red) {
  v = wr_sum(v);
  __syncthreads();
  if ((threadIdx.x & 63) == 0) red[threadIdx.x >> 6] = v;
  __syncthreads();
  return red[0] + red[1] + red[2] + red[3];
}

__device__ __forceinline__ unsigned int bf16rne(float f) {
  unsigned int u = __float_as_uint(f);
  return (u + 0x7fffu + ((u >> 16) & 1u)) >> 16;
}
__device__ __forceinline__ unsigned int packhl(float f) {
  unsigned int hb = bf16rne(f);
  float hf = __uint_as_float(hb << 16);
  unsigned int lb = bf16rne(f - hf);
  return (hb & 0xffffu) | (lb << 16);
}

#define MF(a, b, c) __builtin_amdgcn_mfma_f32_16x16x32_bf16(a, b, c, 0, 0, 0)

__device__ __forceinline__ void loadch(const float* __restrict__ xb, int px0,
                                       int tid, float4* dst) {
#pragma unroll
  for (int it = 0; it < 5; ++it) {
    int idx = it * 256 + tid;
    if (idx < 1088) {
      int c = idx >> 5, p4 = idx & 31;
      dst[it] = *(const float4*)(xb + c * 4096 + px0 + p4 * 4);
    }
  }
}

// =======================================================================
// Kernel A: stream x once. grid = 256 batches x 4 slabs (1024 px each).
// LDS ~25.5 KB (gram merge aliased onto staging tile).
// __launch_bounds__(256,2): do NOT cap VGPRs below the ~92 this kernel
// needs — round 5's (256,4) forced 64 VGPR -> cur/nxt spilled to scratch
// (WRITE_SIZE 20KB->368MB, dur 142->277us). At 92 VGPR (<=128) the HW
// still co-schedules 4 blocks/CU at runtime; LDS allows 6.
// =======================================================================
__global__ void __launch_bounds__(256, 2)
mfeA(const float* __restrict__ x, float* __restrict__ ws) {
  const int bid = blockIdx.x;
  const int b = bid >> 2;
  const int slab = bid & 3;
  const int tid = threadIdx.x;
  const int lane = tid & 63, wv = tid >> 6;
  const float* xb = x + (size_t)b * (34 * 4096);
  const int px_base = slab * 1024;

  __shared__ unsigned int tile[48 * 134];  // interleaved h|l<<16, stride 134
  __shared__ float red[4];

  float4 cur[5], nxt[5];
  loadch(xb, px_base, tid, cur);           // prefetch chunk 0 ASAP

  // zero-pad channels 34..47 (never overwritten)
  for (int i = 34 * 134 + tid; i < 48 * 134; i += 256) tile[i] = 0u;

  f32x4 acc[15];
#pragma unroll
  for (int t = 0; t < 15; ++t) acc[t] = (f32x4){0.f, 0.f, 0.f, 0.f};
  float msl[17];
#pragma unroll
  for (int i = 0; i < 17; ++i) msl[i] = 0.f;
  float tsum = 0.f, tsq = 0.f, dsq = 0.f;

  const int half = lane >> 5, pxi = lane & 31;
  const int wpx = wv * 32;
  const int c0s = half * 17;

#pragma unroll 1
  for (int cj = 0; cj < 8; ++cj) {
    const int px0 = px_base + cj * 128;
    // ---- convert regs (loaded last iter) -> LDS; exact f32 stats ----
#pragma unroll
    for (int it = 0; it < 5; ++it) {
      int idx = it * 256 + tid;
      if (idx < 1088) {
        const float4 v = cur[it];
        tsum += v.x + v.y + v.z + v.w;
        tsq += v.x * v.x + v.y * v.y + v.z * v.z + v.w * v.w;
        int c = idx >> 5, p4 = idx & 31;
        unsigned int base = c * 134 + p4 * 4;
        uint2 w0, w1;
        w0.x = packhl(v.x); w0.y = packhl(v.y);
        w1.x = packhl(v.z); w1.y = packhl(v.w);
        *(uint2*)&tile[base] = w0;
        *(uint2*)&tile[base + 2] = w1;
      }
    }
    __syncthreads();
    // ---- issue next chunk's loads (latency hides under compute) ----
    if (cj < 7) loadch(xb, px0 + 128, tid, nxt);
    // ---- Gram: this wave's 32-px k-step ----
    {
      short8 Ah[3], Al[3];
#pragma unroll
      for (int ct = 0; ct < 3; ++ct) {
        int c = ct * 16 + (lane & 15);
        int iu = c * 134 + wpx + (lane >> 4) * 8;
        uint2 q0 = *(const uint2*)&tile[iu + 0];
        uint2 q1 = *(const uint2*)&tile[iu + 2];
        uint2 q2 = *(const uint2*)&tile[iu + 4];
        uint2 q3 = *(const uint2*)&tile[iu + 6];
        short8 h, l;
        h[0] = (short)(q0.x & 0xffffu); l[0] = (short)(q0.x >> 16);
        h[1] = (short)(q0.y & 0xffffu); l[1] = (short)(q0.y >> 16);
        h[2] = (short)(q1.x & 0xffffu); l[2] = (short)(q1.x >> 16);
        h[3] = (short)(q1.y & 0xffffu); l[3] = (short)(q1.y >> 16);
        h[4] = (short)(q2.x & 0xffffu); l[4] = (short)(q2.x >> 16);
        h[5] = (short)(q2.y & 0xffffu); l[5] = (short)(q2.y >> 16);
        h[6] = (short)(q3.x & 0xffffu); l[6] = (short)(q3.x >> 16);
        h[7] = (short)(q3.y & 0xffffu); l[7] = (short)(q3.y >> 16);
        Ah[ct] = h; Al[ct] = l;
      }
      acc[0] = MF(Ah[0], Ah[0], acc[0]);
      acc[1] = MF(Ah[0], Ah[1], acc[1]);
      acc[2] = MF(Ah[0], Ah[2], acc[2]);
      acc[3] = MF(Ah[1], Ah[1], acc[3]);
      acc[4] = MF(Ah[1], Ah[2], acc[4]);
      acc[5] = MF(Ah[2], Ah[2], acc[5]);
      acc[6]  = MF(Ah[0], Al[0], acc[6]);
      acc[7]  = MF(Ah[0], Al[1], acc[7]);
      acc[8]  = MF(Ah[0], Al[2], acc[8]);
      acc[9]  = MF(Ah[1], Al[0], acc[9]);
      acc[10] = MF(Ah[1], Al[1], acc[10]);
      acc[11] = MF(Ah[1], Al[2], acc[11]);
      acc[12] = MF(Ah[2], Al[0], acc[12]);
      acc[13] = MF(Ah[2], Al[1], acc[13]);
      acc[14] = MF(Ah[2], Al[2], acc[14]);
    }
    // ---- stats from LDS: (wave, half) owns 17 channels x 32 px ----
    {
      float colsum = 0.f, prev = 0.f;
      if (half) {
        unsigned int u = tile[16 * 134 + wpx + pxi];
        prev = __uint_as_float(u << 16) + __uint_as_float(u & 0xffff0000u);
      }
#pragma unroll
      for (int i = 0; i < 17; ++i) {
        unsigned int u = tile[(c0s + i) * 134 + wpx + pxi];
        float v = __uint_as_float(u << 16) + __uint_as_float(u & 0xffff0000u);
        colsum += v; msl[i] += v;
        if (half || i) { float d = v - prev; dsq += d * d; }
        prev = v;
      }
      float tot = colsum + __shfl_xor(colsum, 32, 64);
      if (!half) ws[WS_SP + b * 4096 + px0 + wpx + pxi] = tot * (1.f / 34.f);
    }
    __syncthreads();
    if (cj < 7) {
#pragma unroll
      for (int it = 0; it < 5; ++it) cur[it] = nxt[it];
    }
  }

  // ---- per-channel sums: butterfly across 32 px lanes ----
#pragma unroll
  for (int i = 0; i < 17; ++i) {
    float s = msl[i];
    s += __shfl_xor(s, 1, 64); s += __shfl_xor(s, 2, 64);
    s += __shfl_xor(s, 4, 64); s += __shfl_xor(s, 8, 64);
    s += __shfl_xor(s, 16, 64);
    msl[i] = s;
  }
  if (pxi < 17) {
    float v = 0.f;
#pragma unroll
    for (int i = 0; i < 17; ++i) if (pxi == i) v = msl[i];
    atomicAdd(ws + WS_MS + b * 48 + c0s + pxi, v);
  }

  // ---- scalar stats (atomic, tiny) ----
  float T1 = block_reduce(tsum, red);
  float T2 = block_reduce(tsq, red);
  float T3 = block_reduce(dsq, red);
  if (tid == 0) {
    atomicAdd(ws + WS_SCAL + b * 4 + 0, T1);
    atomicAdd(ws + WS_SCAL + b * 4 + 1, T2);
    atomicAdd(ws + WS_SCAL + b * 4 + 2, T3);
  }

  // ---- Gram: cross-wave merge in LDS (ALIASED onto tile), then store ----
  float* gmerge = (float*)tile;   // needs 3840 floats <= 6432 available
  for (int i = tid; i < 3840; i += 256) gmerge[i] = 0.f;
  __syncthreads();
#pragma unroll
  for (int t = 0; t < 15; ++t)
#pragma unroll
    for (int r = 0; r < 4; ++r)
      atomicAdd(&gmerge[t * 256 + lane * 4 + r], acc[t][r]);
  __syncthreads();
  {
    float* grbase = ws + WS_GR + (size_t)bid * 3840;
    for (int i = tid; i < 960; i += 256)
      *(float4*)(grbase + i * 4) = *(const float4*)&gmerge[i * 4];
  }
}

// =======================================================================
// Kernel B helpers
// =======================================================================
template<int R>
__device__ void hpass(const float* __restrict__ src, float* __restrict__ dst,
                      const float* __restrict__ pf, int tid) {
  const int row = tid >> 2, c0 = (tid & 3) << 4;
  float pr[2 * R + 1];
#pragma unroll
  for (int t = 0; t < 2 * R + 1; ++t) pr[t] = pf[t];
  float w[16 + 2 * R];
#pragma unroll
  for (int k = 0; k < 16 + 2 * R; ++k) {
    int cc = c0 - R + k;
    w[k] = (cc >= 0 && cc < 64) ? src[row * 65 + cc] : 0.f;
  }
#pragma unroll
  for (int o = 0; o < 16; ++o) {
    float a = 0.f;
#pragma unroll
    for (int t = 0; t < 2 * R + 1; ++t) a += pr[t] * w[o + t];
    dst[row * 65 + c0 + o] = a;
  }
}
template<int R>
__device__ void vpass1(const float* __restrict__ H, const float* __restrict__ pf,
                       int tid, float& s1, float& s2) {
  const int c = tid & 63, r0 = (tid >> 6) << 4;
  float pr[2 * R + 1];
#pragma unroll
  for (int t = 0; t < 2 * R + 1; ++t) pr[t] = pf[t];
  float w[16 + 2 * R];
#pragma unroll
  for (int k = 0; k < 16 + 2 * R; ++k) {
    int rr = r0 - R + k;
    w[k] = (rr >= 0 && rr < 64) ? H[rr * 65 + c] : 0.f;
  }
#pragma unroll
  for (int o = 0; o < 16; ++o) {
    float y = 0.f;
#pragma unroll
    for (int t = 0; t < 2 * R + 1; ++t) y += pr[t] * w[o + t];
    s1 += y; s2 += y * y;
  }
}

__device__ __forceinline__ void emit(float* out, int b, int f, float v) {
  v = fminf(fmaxf(v, 0.f), 1.f);
  out[b * 12 + f] = 1.f / (1.f + expf(-v));
}

// =======================================================================
// Kernel B: grid (256 batches, 20 types).
// type 0: gram reduce + ms/corr/scalar -> feats 1,2,4,5,6,9,11
// type 1: boxcount + contrast          -> feats 0,3
// type 2: LBP                          -> feat 10
// type 3: Sobel                        -> feat 8
// types 4-19: ONE gabor component each -> atomicAdd etex acc
//   comp = type-4; sf = comp>>2; u = comp&3 (0:th0 1:th90 2:cc 3:ss)
//   var(th45)+var(th135) == 2var(cc)+2var(ss)  [cov term cancels]
// =======================================================================
__global__ void __launch_bounds__(256)
mfeB(const float* __restrict__ ws, float* __restrict__ out) {
  const int b = blockIdx.x;
  const int type = blockIdx.y;
  const int tid = threadIdx.x;

  __shared__ float sm[2 * 64 * 65];   // sp | H1 (33.3 KB -> 4 blocks/CU)
  __shared__ float prof[40];
  __shared__ float red[4];
  __shared__ int icnt[5];
  __shared__ float sA[48];
  __shared__ float sB[48];

  float* sp = sm;

  if (type == 0) {
    // ------------- gram slab reduce -> LDS, then corr etc -------------
    float* hhL = sm;            // 48x48
    float* hlL = sm + 2304;     // 48x48
    const int TI[15] = {0,0,0,1,1,2, 0,0,0,1,1,1,2,2,2};
    const int TJ[15] = {0,1,2,1,2,2, 0,1,2,0,1,2,0,1,2};
    {
      const float* g0 = ws + WS_GR + (size_t)(b * 4 + 0) * 3840;
      const float* g1 = ws + WS_GR + (size_t)(b * 4 + 1) * 3840;
      const float* g2 = ws + WS_GR + (size_t)(b * 4 + 2) * 3840;
      const float* g3 = ws + WS_GR + (size_t)(b * 4 + 3) * 3840;
      for (int fi = tid; fi < 960; fi += 256) {
        float4 v0 = *(const float4*)(g0 + fi * 4);
        float4 v1 = *(const float4*)(g1 + fi * 4);
        float4 v2 = *(const float4*)(g2 + fi * 4);
        float4 v3 = *(const float4*)(g3 + fi * 4);
        float s0 = v0.x + v1.x + v2.x + v3.x;
        float s1 = v0.y + v1.y + v2.y + v3.y;
        float s2 = v0.z + v1.z + v2.z + v3.z;
        float s3 = v0.w + v1.w + v2.w + v3.w;
        int t = fi >> 6, l = fi & 63;
        int row0 = TI[t] * 16 + (l >> 4) * 4;
        int col = TJ[t] * 16 + (l & 15);
        float* dst = (t < 6) ? hhL : hlL;
        dst[(row0 + 0) * 48 + col] = s0;
        dst[(row0 + 1) * 48 + col] = s1;
        dst[(row0 + 2) * 48 + col] = s2;
        dst[(row0 + 3) * 48 + col] = s3;
      }
    }
    if (tid < 34) sA[tid] = ws[WS_MS + b * 48 + tid] * (1.f / 4096.f);
    __syncthreads();
    if (tid < 34) {
      float m = sA[tid];
      float cii = hhL[tid * 48 + tid] + 2.f * hlL[tid * 48 + tid] - 4096.f * m * m;
      sB[tid] = sqrtf(fmaxf(cii, 0.f));
    }
    __syncthreads();
    float cs = 0.f;
    for (int idx = tid; idx < 1156; idx += 256) {
      int i = idx / 34, j = idx - (idx / 34) * 34;
      float hh = ((i >> 4) <= (j >> 4)) ? hhL[i * 48 + j] : hhL[j * 48 + i];
      float cov = hh + hlL[i * 48 + j] + hlL[j * 48 + i] - 4096.f * sA[i] * sA[j];
      cs += cov / (sB[i] * sB[j]);
    }
    float CS = block_reduce(cs, red);

    if (tid < 64) {
      bool act = tid < 34;
      float mi = act ? sA[tid] : 3.4e38f;
      float mn = wr_min(mi);
      float mx = wr_max(act ? sA[tid] : -3.4e38f);
      float v = act ? (sA[tid] - mn) : 0.f;
      float vs = wr_sum(v);
      float pp = v / (vs + 1e-8f);
      float ent = act ? pp * log2f(pp + 1e-8f) : 0.f;
      float es = wr_sum(ent);
      float fi = act ? -sA[tid] : 0.f;
      float prom = 0.f; bool valid = false;
      if (act) {
        int i = tid, lb = -1, rb = 34;
        for (int j = 0; j < 34; ++j) {
          float fj = -sA[j];
          if (fj > fi) { if (j < i && j > lb) lb = j; if (j > i && j < rb) rb = j; }
        }
        float lmin = 3.4e38f, rmin = 3.4e38f;
        for (int j = lb + 1; j < i; ++j) lmin = fminf(lmin, -sA[j]);
        for (int j = i + 1; j < rb; ++j) rmin = fminf(rmin, -sA[j]);
        prom = fi - fmaxf(lmin, rmin);
        bool ispk = (i > 0) && (i < 33) && (fi > -sA[i - 1]) && (fi > -sA[i + 1]);
        valid = ispk && (prom >= 0.05f);
      }
      float cnt = wr_sum(valid ? 1.f : 0.f);
      float tot = wr_sum(valid ? prom : 0.f);
      if (tid == 0) {
        float T1 = ws[WS_SCAL + b * 4 + 0];
        float T2 = ws[WS_SCAL + b * 4 + 1];
        float T3 = ws[WS_SCAL + b * 4 + 2];
        const float NA = 34.f * 4096.f;
        float mu = T1 / NA;
        float sd = sqrtf(fmaxf(T2 / NA - mu * mu, 0.f));
        float snr = fminf(fmaxf(20.f * log10f(mu / (sd + 1e-8f)), 0.f), 50.f) * (1.f / 50.f);
        const float ND = 33.f * 4096.f;
        float md = (ws[WS_MS + b * 48 + 33] - ws[WS_MS + b * 48 + 0]) / ND;
        emit(out, b, 1, T3 / ND - md * md);                       // sgv
        emit(out, b, 2, snr);                                     // snr
        emit(out, b, 4, -es / (float)5.087462841250339);          // hl
        emit(out, b, 5, mu);                                      // mu
        emit(out, b, 6, (CS - 34.f) / (34.f * 33.f));             // avg_corr
        emit(out, b, 9, mx - mn);                                 // sc
        emit(out, b, 11, (cnt > 0.f) ? tot / cnt : 0.f);          // ad
      }
    }
    return;
  }

  // all other types need the spatial image in LDS (stride 65)
  for (int i = tid; i < 1024; i += 256) {
    float4 v = *(const float4*)(ws + WS_SP + b * 4096 + i * 4);
    int r = i >> 4, c = (i & 15) * 4;
    float* d = &sp[r * 65 + c];
    d[0] = v.x; d[1] = v.y; d[2] = v.z; d[3] = v.w;
  }
  if (type == 1 && tid < 5) icnt[tid] = 0;
  if (type >= 4) {
    const int comp = type - 4;
    const int sf = comp >> 2, u = comp & 3;
    if (tid < 38) {
      int uu = tid / 19, t = tid % 19;   // uu: 0=h profile, 1=v profile
      double sg = (sf >= 2) ? 3.0 : 1.0;
      double fr = (sf & 1) ? 0.3 : 0.1;
      int R = (u < 2) ? ((sf >= 2) ? 9 : 3) : ((sf >= 2) ? 7 : 3);
      float val = 0.f;
      if (t <= 2 * R) {
        double d = (double)(t - R);
        double E = exp(-0.5 * d * d / (sg * sg));
        double nrm = 1.0 / (2.0 * PI_D * sg * sg);
        double w = 2.0 * PI_D * fr;
        double a = w * sqrt(0.5);
        double v = 0.0;
        if (u == 0)      v = uu ? (E * nrm) : (E * cos(w * d));
        else if (u == 1) v = uu ? (E * cos(w * d) * nrm) : E;
        else if (u == 2) v = uu ? (E * cos(a * d) * nrm) : (E * cos(a * d));
        else             v = uu ? (E * sin(a * d) * nrm) : (E * sin(a * d));
        val = (float)v;
      }
      prof[uu * 19 + t] = val;
    }
  }
  __syncthreads();

  if (type == 1) {
    // ------------- boxcount pyramid + contrast -------------
    float* Amx = sm + 4160;
    float* Amn = Amx + 1056;
    float* Bmx = Amx + 2112;
    float* Bmn = Amx + 2384;
    {
      int c2 = 0;
#pragma unroll
      for (int it = 0; it < 4; ++it) {
        int idx = it * 256 + tid;
        int br = idx >> 5, bc = idx & 31;
        int r = br * 2, c = bc * 2;
        float q00 = floorf(sp[r * 65 + c] * 255.f);
        float q01 = floorf(sp[r * 65 + c + 1] * 255.f);
        float q10 = floorf(sp[(r + 1) * 65 + c] * 255.f);
        float q11 = floorf(sp[(r + 1) * 65 + c + 1] * 255.f);
        float mxv = fmaxf(fmaxf(q00, q01), fmaxf(q10, q11));
        float mnv = fminf(fminf(q00, q01), fminf(q10, q11));
        Amx[br * 33 + bc] = mxv; Amn[br * 33 + bc] = mnv;
        if (mxv > mnv) ++c2;
      }
      atomicAdd(&icnt[0], c2);
    }
    __syncthreads();
    {
      int br = tid >> 4, bc = tid & 15;
      int i0 = (br * 2) * 33 + bc * 2;
      float mxv = fmaxf(fmaxf(Amx[i0], Amx[i0 + 1]), fmaxf(Amx[i0 + 33], Amx[i0 + 34]));
      float mnv = fminf(fminf(Amn[i0], Amn[i0 + 1]), fminf(Amn[i0 + 33], Amn[i0 + 34]));
      Bmx[br * 17 + bc] = mxv; Bmn[br * 17 + bc] = mnv;
      if (mxv > mnv) atomicAdd(&icnt[1], 1);
    }
    __syncthreads();
    if (tid < 64) {
      int br = tid >> 3, bc = tid & 7;
      int i0 = (br * 2) * 17 + bc * 2;
      float mxv = fmaxf(fmaxf(Bmx[i0], Bmx[i0 + 1]), fmaxf(Bmx[i0 + 17], Bmx[i0 + 18]));
      float mnv = fminf(fminf(Bmn[i0], Bmn[i0 + 1]), fminf(Bmn[i0 + 17], Bmn[i0 + 18]));
      Amx[br * 9 + bc] = mxv; Amn[br * 9 + bc] = mnv;
      if (mxv > mnv) atomicAdd(&icnt[2], 1);
    }
    __syncthreads();
    if (tid < 16) {
      int br = tid >> 2, bc = tid & 3;
      int i0 = (br * 2) * 9 + bc * 2;
      float mxv = fmaxf(fmaxf(Amx[i0], Amx[i0 + 1]), fmaxf(Amx[i0 + 9], Amx[i0 + 10]));
      float mnv = fminf(fminf(Amn[i0], Amn[i0 + 1]), fminf(Amn[i0 + 9], Amn[i0 + 10]));
      Bmx[br * 5 + bc] = mxv; Bmn[br * 5 + bc] = mnv;
      if (mxv > mnv) atomicAdd(&icnt[3], 1);
    }
    __syncthreads();
    if (tid < 4) {
      int br = tid >> 1, bc = tid & 1;
      int i0 = (br * 2) * 5 + bc * 2;
      float mxv = fmaxf(fmaxf(Bmx[i0], Bmx[i0 + 1]), fmaxf(Bmx[i0 + 5], Bmx[i0 + 6]));
      float mnv = fminf(fminf(Bmn[i0], Bmn[i0 + 1]), fminf(Bmn[i0 + 5], Bmn[i0 + 6]));
      if (mxv > mnv) atomicAdd(&icnt[4], 1);
    }
    float contr = 0.f;
#pragma unroll 4
    for (int k = 0; k < 16; ++k) {
      int p = k * 256 + tid;
      int r = p >> 6, c = p & 63;
      if (c < 63) {
        float d = floorf(sp[r * 65 + c] * 255.f) - floorf(sp[r * 65 + c + 1] * 255.f);
        contr += d * d;
      }
    }
    float CTt = block_reduce(contr, red);
    if (tid == 0) {
      float cm = CTt * (1.f / 4032.f);
      emit(out, b, 3, 1.f / (1.f + cm * 0.01f));   // hs
      float lxv[5] = {logf(2.f), logf(4.f), logf(8.f), logf(16.f), logf(32.f)};
      float lxm = (lxv[0] + lxv[1] + lxv[2] + lxv[3] + lxv[4]) * 0.2f;
      float num = 0.f, den = 0.f;
#pragma unroll
      for (int i = 0; i < 5; ++i) {
        float cntf = fmaxf((float)icnt[i], 1.f);
        float lc = lxv[i] - lxm;
        num += logf(cntf) * lc;
        den += lc * lc;
      }
      emit(out, b, 0, fminf(fmaxf(-(num / den), 1.f), 2.f));   // df
    }
  } else if (type == 2) {
    // ------------- LBP variance -------------
    const double Sd = sqrt(0.5);
    const float W_A = (float)(Sd * (1.0 - Sd));
    const float W_B = (float)(Sd * Sd);
    const float W_C = (float)((1.0 - Sd) * (1.0 - Sd));
    float ls = 0.f, ls2 = 0.f;
#pragma unroll 4
    for (int k = 0; k < 16; ++k) {
      int p = k * 256 + tid;
      int r = p >> 6, c = p & 63;
      float n[3][3];
#pragma unroll
      for (int i = 0; i < 3; ++i)
#pragma unroll
        for (int j = 0; j < 3; ++j) {
          int rr = r + i - 1, cc = c + j - 1;
          n[i][j] = (rr >= 0 && rr < 64 && cc >= 0 && cc < 64) ? sp[rr * 65 + cc] : 0.f;
        }
      float ctr = n[1][1];
      float v1 = W_A * n[0][1] + W_B * n[0][2] + W_C * n[1][1] + W_A * n[1][2];
      float v3 = W_B * n[0][0] + W_A * n[0][1] + W_A * n[1][0] + W_C * n[1][1];
      float v5 = W_A * n[1][0] + W_C * n[1][1] + W_B * n[2][0] + W_A * n[2][1];
      float v7 = W_C * n[1][1] + W_A * n[1][2] + W_A * n[2][1] + W_B * n[2][2];
      bool bt[8];
      bt[0] = n[1][2] >= ctr; bt[1] = v1 >= ctr; bt[2] = n[0][1] >= ctr; bt[3] = v3 >= ctr;
      bt[4] = n[1][0] >= ctr; bt[5] = v5 >= ctr; bt[6] = n[2][1] >= ctr; bt[7] = v7 >= ctr;
      int ones = 0, trans = 0;
#pragma unroll
      for (int q = 0; q < 8; ++q) { ones += bt[q] ? 1 : 0; trans += (bt[q] != bt[(q + 1) & 7]) ? 1 : 0; }
      float lbp = (trans <= 2) ? (float)ones : 9.f;
      ls += lbp; ls2 += lbp * lbp;
    }
    float S1 = block_reduce(ls, red), S2 = block_reduce(ls2, red);
    if (tid == 0) {
      float m = S1 * (1.f / 4096.f);
      emit(out, b, 10, fminf(1.f, (S2 * (1.f / 4096.f) - m * m) * 0.01f));  // lbpv
    }
  } else if (type == 3) {
    // ------------- Sobel edge fraction -------------
    int ec = 0;
#pragma unroll 4
    for (int k = 0; k < 16; ++k) {
      int p = k * 256 + tid;
      int r = p >> 6, c = p & 63;
      float P[3][3];
#pragma unroll
      for (int i = 0; i < 3; ++i)
#pragma unroll
        for (int j = 0; j < 3; ++j) {
          int rr = min(max(r + i - 1, 0), 63);
          int cc = min(max(c + j - 1, 0), 63);
          P[i][j] = sp[rr * 65 + cc];
        }
      float gx = (P[0][2] - P[0][0]) + 2.f * (P[1][2] - P[1][0]) + (P[2][2] - P[2][0]);
      float gy = (P[2][0] - P[0][0]) + 2.f * (P[2][1] - P[0][1]) + (P[2][2] - P[0][2]);
      if (gx * gx + gy * gy > 0.01f) ++ec;
    }
    float E = block_reduce((float)ec, red);
    if (tid == 0) emit(out, b, 8, E * (1.f / 4096.f));  // edge
  } else {
    // ------------- Gabor: ONE separable component per block -------------
    const int comp = type - 4;
    const int sf = comp >> 2, u = comp & 3;
    float* H1 = sm + 4160;
    float s1 = 0.f, s2 = 0.f;
    if (sf < 2) {
      hpass<3>(sp, H1, prof, tid); __syncthreads();
      vpass1<3>(H1, prof + 19, tid, s1, s2);
    } else if (u < 2) {
      hpass<9>(sp, H1, prof, tid); __syncthreads();
      vpass1<9>(H1, prof + 19, tid, s1, s2);
    } else {
      hpass<7>(sp, H1, prof, tid); __syncthreads();
      vpass1<7>(H1, prof + 19, tid, s1, s2);
    }
    float S1 = block_reduce(s1, red), S2 = block_reduce(s2, red);
    if (tid == 0) {
      const float inv = 1.f / 4096.f;
      float var = S2 * inv - (S1 * inv) * (S1 * inv);
      float wgt = (u < 2) ? 1.f : 2.f;   // diag pair: var sum = 2var(cc)+2var(ss)
      atomicAdd((float*)(ws + WS_ETEX + b), wgt * var * (1.f / 1600.f));
    }
  }
}

// =======================================================================
// Kernel C: finalize etex (feat 7) after all gabor blocks accumulated.
// =======================================================================
__global__ void __launch_bounds__(256)
mfeC(const float* __restrict__ ws, float* __restrict__ out) {
  int b = threadIdx.x;
  emit(out, b, 7, ws[WS_ETEX + b]);
}

extern "C" void kernel_launch(void* const* d_in, const int* in_sizes, int n_in,
                              void* d_out, int out_size, void* d_ws, size_t ws_size,
                              hipStream_t stream) {
  (void)in_sizes; (void)n_in; (void)out_size;
  // Needs ~20 MB scratch; bail cleanly (clean failed-verify) if undersized.
  if (ws_size < (size_t)WS_TOTAL * sizeof(float)) return;
  const float* x = (const float*)d_in[0];
  float* out = (float*)d_out;
  float* ws = (float*)d_ws;
  // zero only the atomic-accumulated regions (MS, SCAL, ETEX) — 54 KB
  hipMemsetAsync((char*)d_ws + (size_t)WS_MS * 4, 0,
                 (size_t)(WS_TOTAL - WS_MS) * 4, stream);
  hipLaunchKernelGGL(mfeA, dim3(1024), dim3(256), 0, stream, x, ws);
  hipLaunchKernelGGL(mfeB, dim3(256, 20), dim3(256), 0, stream, ws, out);
  hipLaunchKernelGGL(mfeC, dim3(1), dim3(256), 0, stream, ws, out);
}

// Round 7
// 250.924 us; speedup vs baseline: 1.8014x; 1.2846x over previous
//
#include <hip/hip_runtime.h>
#include <math.h>

#define PI_D 3.141592653589793238462643383279502884

typedef __attribute__((ext_vector_type(8))) short short8;
typedef __attribute__((ext_vector_type(4))) float f32x4;

#define TS 38              // per-wave LDS tile stride (u32): even (b64 align), odd/16 banks
#define WTILE (48 * TS)    // 1824 u32 per wave

// ---- ws layout (float units) ----
#define WS_SP    0            // 256*4096 spatial images
#define WS_GR    1048576      // 1024 blocks * 1536 floats gram partials (6 tiles)
#define WS_MS    2621440      // 256*48 per-channel sums (atomic)
#define WS_SCAL  2633728      // 256*4 (tsum,tsq,dsq) (atomic)
#define WS_ETEX  2634752      // 256 etex accumulators (atomic)
#define WS_TOTAL 2635008

__device__ __forceinline__ float wr_sum(float v) {
#pragma unroll
  for (int o = 32; o; o >>= 1) v += __shfl_xor(v, o, 64);
  return v;
}
__device__ __forceinline__ float wr_min(float v) {
#pragma unroll
  for (int o = 32; o; o >>= 1) v = fminf(v, __shfl_xor(v, o, 64));
  return v;
}
__device__ __forceinline__ float wr_max(float v) {
#pragma unroll
  for (int o = 32; o; o >>= 1) v = fmaxf(v, __shfl_xor(v, o, 64));
  return v;
}
__device__ float block_reduce(float v, float* red) {
  v = wr_sum(v);
  __syncthreads();
  if ((threadIdx.x & 63) == 0) red[threadIdx.x >> 6] = v;
  __syncthreads();
  return red[0] + red[1] + red[2] + red[3];
}

__device__ __forceinline__ unsigned int bf16rne(float f) {
  unsigned int u = __float_as_uint(f);
  return (u + 0x7fffu + ((u >> 16) & 1u)) >> 16;
}
__device__ __forceinline__ unsigned int packhl(float f) {
  unsigned int hb = bf16rne(f);
  float hf = __uint_as_float(hb << 16);
  unsigned int lb = bf16rne(f - hf);
  return (hb & 0xffffu) | (lb << 16);
}
__device__ __forceinline__ float unpackhl(unsigned int u) {
  return __uint_as_float(u << 16) + __uint_as_float(u & 0xffff0000u);
}

#define MF(a, b, c) __builtin_amdgcn_mfma_f32_16x16x32_bf16(a, b, c, 0, 0, 0)

// =======================================================================
// Kernel A: stream x once. grid = 256 batches x 4 slabs; each WAVE owns
// a 256-px strip, processed in 8 chunks of 32 px from a wave-PRIVATE LDS
// tile -> NO barriers in the main loop (waves fully autonomous).
// Gram via 3-slot trick: M = HH + LH + HL in ONE 6-tile accumulator set
// (24 regs vs 60) -> unified VGPR+AGPR total ~120 -> 4 waves/SIMD tier.
// =======================================================================
__global__ void __launch_bounds__(256, 2)
mfeA(const float* __restrict__ x, float* __restrict__ ws) {
  const int bid = blockIdx.x;
  const int b = bid >> 2, slab = bid & 3;
  const int tid = threadIdx.x;
  const int lane = tid & 63, wv = tid >> 6;
  const float* xb = x + (size_t)b * (34 * 4096);
  const int wpx_base = slab * 1024 + wv * 256;

  __shared__ unsigned int tileAll[4 * WTILE];   // 29184 B
  __shared__ float red[4];
  unsigned int* tile = tileAll + wv * WTILE;

#define LOADW(px, dst)                                                       \
  do {                                                                       \
    _Pragma("unroll") for (int it_ = 0; it_ < 4; ++it_) {                    \
      int fx_ = it_ * 64 + lane;                                             \
      dst[it_] = *(const float4*)(xb + (fx_ >> 3) * 4096 + (px) + (fx_ & 7) * 4); \
    }                                                                        \
    if (lane < 16) {                                                         \
      int fx_ = 256 + lane;                                                  \
      dst[4] = *(const float4*)(xb + (fx_ >> 3) * 4096 + (px) + (fx_ & 7) * 4); \
    }                                                                        \
  } while (0)

  float4 cur[5], nxt[5];
  LOADW(wpx_base, cur);   // prefetch chunk 0 ASAP

  // zero pad channels 34..47 of own wave tile (wave-coherent, no barrier)
  for (int i = lane; i < 14 * TS; i += 64) tile[34 * TS + i] = 0u;

  f32x4 acc[6];
#pragma unroll
  for (int t = 0; t < 6; ++t) acc[t] = (f32x4){0.f, 0.f, 0.f, 0.f};
  float msl[17];
#pragma unroll
  for (int i = 0; i < 17; ++i) msl[i] = 0.f;
  float tsum = 0.f, tsq = 0.f, dsq = 0.f;

  const int half = lane >> 5, pxi = lane & 31;
  const int c0s = half * 17;

#pragma unroll 1
  for (int cj = 0; cj < 8; ++cj) {
    const int px0 = wpx_base + cj * 32;
    if (cj < 7) LOADW(px0 + 32, nxt);   // issue next chunk's loads early
    // ---- convert cur -> wave tile; exact f32 stats ----
#pragma unroll
    for (int it = 0; it < 5; ++it) {
      if (it < 4 || lane < 16) {
        const float4 v = cur[it];
        tsum += v.x + v.y + v.z + v.w;
        tsq += v.x * v.x + v.y * v.y + v.z * v.z + v.w * v.w;
        int fidx = it * 64 + lane;
        unsigned int base = (unsigned)(fidx >> 3) * TS + (fidx & 7) * 4;
        uint2 w0, w1;
        w0.x = packhl(v.x); w0.y = packhl(v.y);
        w1.x = packhl(v.z); w1.y = packhl(v.w);
        *(uint2*)&tile[base] = w0;
        *(uint2*)&tile[base + 2] = w1;
      }
    }
    // ---- Gram fragments (wave-private tile; compiler orders via lgkmcnt) ----
    {
      short8 Ah[3], Al[3];
#pragma unroll
      for (int ct = 0; ct < 3; ++ct) {
        int c = ct * 16 + (lane & 15);
        int iu = c * TS + (lane >> 4) * 8;
        uint2 q0 = *(const uint2*)&tile[iu + 0];
        uint2 q1 = *(const uint2*)&tile[iu + 2];
        uint2 q2 = *(const uint2*)&tile[iu + 4];
        uint2 q3 = *(const uint2*)&tile[iu + 6];
        short8 h, l;
        h[0] = (short)(q0.x & 0xffffu); l[0] = (short)(q0.x >> 16);
        h[1] = (short)(q0.y & 0xffffu); l[1] = (short)(q0.y >> 16);
        h[2] = (short)(q1.x & 0xffffu); l[2] = (short)(q1.x >> 16);
        h[3] = (short)(q1.y & 0xffffu); l[3] = (short)(q1.y >> 16);
        h[4] = (short)(q2.x & 0xffffu); l[4] = (short)(q2.x >> 16);
        h[5] = (short)(q2.y & 0xffffu); l[5] = (short)(q2.y >> 16);
        h[6] = (short)(q3.x & 0xffffu); l[6] = (short)(q3.x >> 16);
        h[7] = (short)(q3.y & 0xffffu); l[7] = (short)(q3.y >> 16);
        Ah[ct] = h; Al[ct] = l;
      }
      // 3-slot accumulation: acc(ti,tj) += h_i h_j + l_i h_j + h_i l_j
      acc[0] = MF(Ah[0], Ah[0], acc[0]);
      acc[0] = MF(Al[0], Ah[0], acc[0]);
      acc[0] = MF(Ah[0], Al[0], acc[0]);
      acc[1] = MF(Ah[0], Ah[1], acc[1]);
      acc[1] = MF(Al[0], Ah[1], acc[1]);
      acc[1] = MF(Ah[0], Al[1], acc[1]);
      acc[2] = MF(Ah[0], Ah[2], acc[2]);
      acc[2] = MF(Al[0], Ah[2], acc[2]);
      acc[2] = MF(Ah[0], Al[2], acc[2]);
      acc[3] = MF(Ah[1], Ah[1], acc[3]);
      acc[3] = MF(Al[1], Ah[1], acc[3]);
      acc[3] = MF(Ah[1], Al[1], acc[3]);
      acc[4] = MF(Ah[1], Ah[2], acc[4]);
      acc[4] = MF(Al[1], Ah[2], acc[4]);
      acc[4] = MF(Ah[1], Al[2], acc[4]);
      acc[5] = MF(Ah[2], Ah[2], acc[5]);
      acc[5] = MF(Al[2], Ah[2], acc[5]);
      acc[5] = MF(Ah[2], Al[2], acc[5]);
    }
    // ---- stats: (half) owns 17 channels at px = pxi of this chunk ----
    {
      float colsum = 0.f, prev = 0.f;
      if (half) prev = unpackhl(tile[16 * TS + pxi]);
#pragma unroll
      for (int i = 0; i < 17; ++i) {
        float v = unpackhl(tile[(c0s + i) * TS + pxi]);
        colsum += v; msl[i] += v;
        if (half || i) { float d = v - prev; dsq += d * d; }
        prev = v;
      }
      float tot = colsum + __shfl_xor(colsum, 32, 64);
      if (!half) ws[WS_SP + b * 4096 + px0 + pxi] = tot * (1.f / 34.f);
    }
    if (cj < 7) {
#pragma unroll
      for (int it = 0; it < 5; ++it) cur[it] = nxt[it];
    }
  }

  // ---- per-channel sums: butterfly across 32 px lanes ----
#pragma unroll
  for (int i = 0; i < 17; ++i) {
    float s = msl[i];
    s += __shfl_xor(s, 1, 64); s += __shfl_xor(s, 2, 64);
    s += __shfl_xor(s, 4, 64); s += __shfl_xor(s, 8, 64);
    s += __shfl_xor(s, 16, 64);
    msl[i] = s;
  }
  if (pxi < 17) {
    float v = 0.f;
#pragma unroll
    for (int i = 0; i < 17; ++i) if (pxi == i) v = msl[i];
    atomicAdd(ws + WS_MS + b * 48 + c0s + pxi, v);
  }

  // ---- scalar stats (block_reduce barriers also sync waves pre-merge) ----
  float T1 = block_reduce(tsum, red);
  float T2 = block_reduce(tsq, red);
  float T3 = block_reduce(dsq, red);
  if (tid == 0) {
    atomicAdd(ws + WS_SCAL + b * 4 + 0, T1);
    atomicAdd(ws + WS_SCAL + b * 4 + 1, T2);
    atomicAdd(ws + WS_SCAL + b * 4 + 2, T3);
  }

  // ---- gram merge: waves write own region (aliases tiles; all done) ----
  float* gm = (float*)tileAll;
#pragma unroll
  for (int t = 0; t < 6; ++t)
#pragma unroll
    for (int r = 0; r < 4; ++r)
      gm[wv * 1536 + t * 256 + lane * 4 + r] = acc[t][r];
  __syncthreads();
  {
    const float4* g4 = (const float4*)gm;
    for (int i = tid; i < 384; i += 256) {
      float4 a = g4[i], b4 = g4[384 + i], c4 = g4[768 + i], d4 = g4[1152 + i];
      float4 s;
      s.x = a.x + b4.x + c4.x + d4.x;
      s.y = a.y + b4.y + c4.y + d4.y;
      s.z = a.z + b4.z + c4.z + d4.z;
      s.w = a.w + b4.w + c4.w + d4.w;
      *(float4*)(ws + WS_GR + (size_t)bid * 1536 + i * 4) = s;
    }
  }
#undef LOADW
}

// =======================================================================
// Kernel B helpers
// =======================================================================
template<int R>
__device__ void hpass(const float* __restrict__ src, float* __restrict__ dst,
                      const float* __restrict__ pf, int tid) {
  const int row = tid >> 2, c0 = (tid & 3) << 4;
  float pr[2 * R + 1];
#pragma unroll
  for (int t = 0; t < 2 * R + 1; ++t) pr[t] = pf[t];
  float w[16 + 2 * R];
#pragma unroll
  for (int k = 0; k < 16 + 2 * R; ++k) {
    int cc = c0 - R + k;
    w[k] = (cc >= 0 && cc < 64) ? src[row * 65 + cc] : 0.f;
  }
#pragma unroll
  for (int o = 0; o < 16; ++o) {
    float a = 0.f;
#pragma unroll
    for (int t = 0; t < 2 * R + 1; ++t) a += pr[t] * w[o + t];
    dst[row * 65 + c0 + o] = a;
  }
}
template<int R>
__device__ void vpass1(const float* __restrict__ H, const float* __restrict__ pf,
                       int tid, float& s1, float& s2) {
  const int c = tid & 63, r0 = (tid >> 6) << 4;
  float pr[2 * R + 1];
#pragma unroll
  for (int t = 0; t < 2 * R + 1; ++t) pr[t] = pf[t];
  float w[16 + 2 * R];
#pragma unroll
  for (int k = 0; k < 16 + 2 * R; ++k) {
    int rr = r0 - R + k;
    w[k] = (rr >= 0 && rr < 64) ? H[rr * 65 + c] : 0.f;
  }
#pragma unroll
  for (int o = 0; o < 16; ++o) {
    float y = 0.f;
#pragma unroll
    for (int t = 0; t < 2 * R + 1; ++t) y += pr[t] * w[o + t];
    s1 += y; s2 += y * y;
  }
}

__device__ __forceinline__ void emit(float* out, int b, int f, float v) {
  v = fminf(fmaxf(v, 0.f), 1.f);
  out[b * 12 + f] = 1.f / (1.f + expf(-v));
}

// =======================================================================
// Kernel B: grid (256 batches, 20 types).
// type 0: gram reduce + ms/corr/scalar -> feats 1,2,4,5,6,9,11
// type 1: boxcount + contrast          -> feats 0,3
// type 2: LBP                          -> feat 10
// type 3: Sobel                        -> feat 8
// types 4-19: ONE gabor component each -> atomicAdd etex acc
// =======================================================================
__global__ void __launch_bounds__(256)
mfeB(const float* __restrict__ ws, float* __restrict__ out) {
  const int b = blockIdx.x;
  const int type = blockIdx.y;
  const int tid = threadIdx.x;

  __shared__ float sm[2 * 64 * 65];   // sp | H1  (33.3 KB)
  __shared__ float prof[40];
  __shared__ float red[4];
  __shared__ int icnt[5];
  __shared__ float sA[48];
  __shared__ float sB[48];

  float* sp = sm;

  if (type == 0) {
    // ------------- gram slab reduce -> symmetric M in LDS -------------
    float* mL = sm;   // 48x48
    const int TI[6] = {0, 0, 0, 1, 1, 2};
    const int TJ[6] = {0, 1, 2, 1, 2, 2};
    {
      const float4* g0 = (const float4*)(ws + WS_GR + (size_t)(b * 4 + 0) * 1536);
      const float4* g1 = (const float4*)(ws + WS_GR + (size_t)(b * 4 + 1) * 1536);
      const float4* g2 = (const float4*)(ws + WS_GR + (size_t)(b * 4 + 2) * 1536);
      const float4* g3 = (const float4*)(ws + WS_GR + (size_t)(b * 4 + 3) * 1536);
      for (int fi = tid; fi < 384; fi += 256) {
        float4 v0 = g0[fi], v1 = g1[fi], v2 = g2[fi], v3 = g3[fi];
        float sv[4];
        sv[0] = v0.x + v1.x + v2.x + v3.x;
        sv[1] = v0.y + v1.y + v2.y + v3.y;
        sv[2] = v0.z + v1.z + v2.z + v3.z;
        sv[3] = v0.w + v1.w + v2.w + v3.w;
        int t = fi >> 6, l = fi & 63;
        int row0 = TI[t] * 16 + (l >> 4) * 4;
        int col = TJ[t] * 16 + (l & 15);
        bool offdiag = (t == 1 || t == 2 || t == 4);
#pragma unroll
        for (int r = 0; r < 4; ++r) {
          mL[(row0 + r) * 48 + col] = sv[r];
          if (offdiag) mL[col * 48 + row0 + r] = sv[r];
        }
      }
    }
    if (tid < 34) sA[tid] = ws[WS_MS + b * 48 + tid] * (1.f / 4096.f);
    __syncthreads();
    if (tid < 34) {
      float m = sA[tid];
      float cii = mL[tid * 48 + tid] - 4096.f * m * m;
      sB[tid] = sqrtf(fmaxf(cii, 0.f));
    }
    __syncthreads();
    float cs = 0.f;
    for (int idx = tid; idx < 1156; idx += 256) {
      int i = idx / 34, j = idx - (idx / 34) * 34;
      float cov = mL[i * 48 + j] - 4096.f * sA[i] * sA[j];
      cs += cov / (sB[i] * sB[j]);
    }
    float CS = block_reduce(cs, red);

    if (tid < 64) {
      bool act = tid < 34;
      float mi = act ? sA[tid] : 3.4e38f;
      float mn = wr_min(mi);
      float mx = wr_max(act ? sA[tid] : -3.4e38f);
      float v = act ? (sA[tid] - mn) : 0.f;
      float vs = wr_sum(v);
      float pp = v / (vs + 1e-8f);
      float ent = act ? pp * log2f(pp + 1e-8f) : 0.f;
      float es = wr_sum(ent);
      float fi = act ? -sA[tid] : 0.f;
      float prom = 0.f; bool valid = false;
      if (act) {
        int i = tid, lb = -1, rb = 34;
        for (int j = 0; j < 34; ++j) {
          float fj = -sA[j];
          if (fj > fi) { if (j < i && j > lb) lb = j; if (j > i && j < rb) rb = j; }
        }
        float lmin = 3.4e38f, rmin = 3.4e38f;
        for (int j = lb + 1; j < i; ++j) lmin = fminf(lmin, -sA[j]);
        for (int j = i + 1; j < rb; ++j) rmin = fminf(rmin, -sA[j]);
        prom = fi - fmaxf(lmin, rmin);
        bool ispk = (i > 0) && (i < 33) && (fi > -sA[i - 1]) && (fi > -sA[i + 1]);
        valid = ispk && (prom >= 0.05f);
      }
      float cnt = wr_sum(valid ? 1.f : 0.f);
      float tot = wr_sum(valid ? prom : 0.f);
      if (tid == 0) {
        float T1 = ws[WS_SCAL + b * 4 + 0];
        float T2 = ws[WS_SCAL + b * 4 + 1];
        float T3 = ws[WS_SCAL + b * 4 + 2];
        const float NA = 34.f * 4096.f;
        float mu = T1 / NA;
        float sd = sqrtf(fmaxf(T2 / NA - mu * mu, 0.f));
        float snr = fminf(fmaxf(20.f * log10f(mu / (sd + 1e-8f)), 0.f), 50.f) * (1.f / 50.f);
        const float ND = 33.f * 4096.f;
        float md = (ws[WS_MS + b * 48 + 33] - ws[WS_MS + b * 48 + 0]) / ND;
        emit(out, b, 1, T3 / ND - md * md);                       // sgv
        emit(out, b, 2, snr);                                     // snr
        emit(out, b, 4, -es / (float)5.087462841250339);          // hl
        emit(out, b, 5, mu);                                      // mu
        emit(out, b, 6, (CS - 34.f) / (34.f * 33.f));             // avg_corr
        emit(out, b, 9, mx - mn);                                 // sc
        emit(out, b, 11, (cnt > 0.f) ? tot / cnt : 0.f);          // ad
      }
    }
    return;
  }

  // all other types need the spatial image in LDS (stride 65)
  for (int i = tid; i < 1024; i += 256) {
    float4 v = *(const float4*)(ws + WS_SP + b * 4096 + i * 4);
    int r = i >> 4, c = (i & 15) * 4;
    float* d = &sp[r * 65 + c];
    d[0] = v.x; d[1] = v.y; d[2] = v.z; d[3] = v.w;
  }
  if (type == 1 && tid < 5) icnt[tid] = 0;
  if (type >= 4) {
    const int comp = type - 4;
    const int sf = comp >> 2, u = comp & 3;
    if (tid < 38) {
      int uu = tid / 19, t = tid % 19;   // uu: 0=h profile, 1=v profile
      double sg = (sf >= 2) ? 3.0 : 1.0;
      double fr = (sf & 1) ? 0.3 : 0.1;
      int R = (u < 2) ? ((sf >= 2) ? 9 : 3) : ((sf >= 2) ? 7 : 3);
      float val = 0.f;
      if (t <= 2 * R) {
        double d = (double)(t - R);
        double E = exp(-0.5 * d * d / (sg * sg));
        double nrm = 1.0 / (2.0 * PI_D * sg * sg);
        double w = 2.0 * PI_D * fr;
        double a = w * sqrt(0.5);
        double v = 0.0;
        if (u == 0)      v = uu ? (E * nrm) : (E * cos(w * d));
        else if (u == 1) v = uu ? (E * cos(w * d) * nrm) : E;
        else if (u == 2) v = uu ? (E * cos(a * d) * nrm) : (E * cos(a * d));
        else             v = uu ? (E * sin(a * d) * nrm) : (E * sin(a * d));
        val = (float)v;
      }
      prof[uu * 19 + t] = val;
    }
  }
  __syncthreads();

  if (type == 1) {
    // ------------- boxcount pyramid + contrast -------------
    float* Amx = sm + 4160;
    float* Amn = Amx + 1056;
    float* Bmx = Amx + 2112;
    float* Bmn = Amx + 2384;
    {
      int c2 = 0;
#pragma unroll
      for (int it = 0; it < 4; ++it) {
        int idx = it * 256 + tid;
        int br = idx >> 5, bc = idx & 31;
        int r = br * 2, c = bc * 2;
        float q00 = floorf(sp[r * 65 + c] * 255.f);
        float q01 = floorf(sp[r * 65 + c + 1] * 255.f);
        float q10 = floorf(sp[(r + 1) * 65 + c] * 255.f);
        float q11 = floorf(sp[(r + 1) * 65 + c + 1] * 255.f);
        float mxv = fmaxf(fmaxf(q00, q01), fmaxf(q10, q11));
        float mnv = fminf(fminf(q00, q01), fminf(q10, q11));
        Amx[br * 33 + bc] = mxv; Amn[br * 33 + bc] = mnv;
        if (mxv > mnv) ++c2;
      }
      atomicAdd(&icnt[0], c2);
    }
    __syncthreads();
    {
      int br = tid >> 4, bc = tid & 15;
      int i0 = (br * 2) * 33 + bc * 2;
      float mxv = fmaxf(fmaxf(Amx[i0], Amx[i0 + 1]), fmaxf(Amx[i0 + 33], Amx[i0 + 34]));
      float mnv = fminf(fminf(Amn[i0], Amn[i0 + 1]), fminf(Amn[i0 + 33], Amn[i0 + 34]));
      Bmx[br * 17 + bc] = mxv; Bmn[br * 17 + bc] = mnv;
      if (mxv > mnv) atomicAdd(&icnt[1], 1);
    }
    __syncthreads();
    if (tid < 64) {
      int br = tid >> 3, bc = tid & 7;
      int i0 = (br * 2) * 17 + bc * 2;
      float mxv = fmaxf(fmaxf(Bmx[i0], Bmx[i0 + 1]), fmaxf(Bmx[i0 + 17], Bmx[i0 + 18]));
      float mnv = fminf(fminf(Bmn[i0], Bmn[i0 + 1]), fminf(Bmn[i0 + 17], Bmn[i0 + 18]));
      Amx[br * 9 + bc] = mxv; Amn[br * 9 + bc] = mnv;
      if (mxv > mnv) atomicAdd(&icnt[2], 1);
    }
    __syncthreads();
    if (tid < 16) {
      int br = tid >> 2, bc = tid & 3;
      int i0 = (br * 2) * 9 + bc * 2;
      float mxv = fmaxf(fmaxf(Amx[i0], Amx[i0 + 1]), fmaxf(Amx[i0 + 9], Amx[i0 + 10]));
      float mnv = fminf(fminf(Amn[i0], Amn[i0 + 1]), fminf(Amn[i0 + 9], Amn[i0 + 10]));
      Bmx[br * 5 + bc] = mxv; Bmn[br * 5 + bc] = mnv;
      if (mxv > mnv) atomicAdd(&icnt[3], 1);
    }
    __syncthreads();
    if (tid < 4) {
      int br = tid >> 1, bc = tid & 1;
      int i0 = (br * 2) * 5 + bc * 2;
      float mxv = fmaxf(fmaxf(Bmx[i0], Bmx[i0 + 1]), fmaxf(Bmx[i0 + 5], Bmx[i0 + 6]));
      float mnv = fminf(fminf(Bmn[i0], Bmn[i0 + 1]), fminf(Bmn[i0 + 5], Bmn[i0 + 6]));
      if (mxv > mnv) atomicAdd(&icnt[4], 1);
    }
    float contr = 0.f;
#pragma unroll 4
    for (int k = 0; k < 16; ++k) {
      int p = k * 256 + tid;
      int r = p >> 6, c = p & 63;
      if (c < 63) {
        float d = floorf(sp[r * 65 + c] * 255.f) - floorf(sp[r * 65 + c + 1] * 255.f);
        contr += d * d;
      }
    }
    float CTt = block_reduce(contr, red);
    if (tid == 0) {
      float cm = CTt * (1.f / 4032.f);
      emit(out, b, 3, 1.f / (1.f + cm * 0.01f));   // hs
      float lxv[5] = {logf(2.f), logf(4.f), logf(8.f), logf(16.f), logf(32.f)};
      float lxm = (lxv[0] + lxv[1] + lxv[2] + lxv[3] + lxv[4]) * 0.2f;
      float num = 0.f, den = 0.f;
#pragma unroll
      for (int i = 0; i < 5; ++i) {
        float cntf = fmaxf((float)icnt[i], 1.f);
        float lc = lxv[i] - lxm;
        num += logf(cntf) * lc;
        den += lc * lc;
      }
      emit(out, b, 0, fminf(fmaxf(-(num / den), 1.f), 2.f));   // df
    }
  } else if (type == 2) {
    // ------------- LBP variance -------------
    const double Sd = sqrt(0.5);
    const float W_A = (float)(Sd * (1.0 - Sd));
    const float W_B = (float)(Sd * Sd);
    const float W_C = (float)((1.0 - Sd) * (1.0 - Sd));
    float ls = 0.f, ls2 = 0.f;
#pragma unroll 4
    for (int k = 0; k < 16; ++k) {
      int p = k * 256 + tid;
      int r = p >> 6, c = p & 63;
      float n[3][3];
#pragma unroll
      for (int i = 0; i < 3; ++i)
#pragma unroll
        for (int j = 0; j < 3; ++j) {
          int rr = r + i - 1, cc = c + j - 1;
          n[i][j] = (rr >= 0 && rr < 64 && cc >= 0 && cc < 64) ? sp[rr * 65 + cc] : 0.f;
        }
      float ctr = n[1][1];
      float v1 = W_A * n[0][1] + W_B * n[0][2] + W_C * n[1][1] + W_A * n[1][2];
      float v3 = W_B * n[0][0] + W_A * n[0][1] + W_A * n[1][0] + W_C * n[1][1];
      float v5 = W_A * n[1][0] + W_C * n[1][1] + W_B * n[2][0] + W_A * n[2][1];
      float v7 = W_C * n[1][1] + W_A * n[1][2] + W_A * n[2][1] + W_B * n[2][2];
      bool bt[8];
      bt[0] = n[1][2] >= ctr; bt[1] = v1 >= ctr; bt[2] = n[0][1] >= ctr; bt[3] = v3 >= ctr;
      bt[4] = n[1][0] >= ctr; bt[5] = v5 >= ctr; bt[6] = n[2][1] >= ctr; bt[7] = v7 >= ctr;
      int ones = 0, trans = 0;
#pragma unroll
      for (int q = 0; q < 8; ++q) { ones += bt[q] ? 1 : 0; trans += (bt[q] != bt[(q + 1) & 7]) ? 1 : 0; }
      float lbp = (trans <= 2) ? (float)ones : 9.f;
      ls += lbp; ls2 += lbp * lbp;
    }
    float S1 = block_reduce(ls, red), S2 = block_reduce(ls2, red);
    if (tid == 0) {
      float m = S1 * (1.f / 4096.f);
      emit(out, b, 10, fminf(1.f, (S2 * (1.f / 4096.f) - m * m) * 0.01f));  // lbpv
    }
  } else if (type == 3) {
    // ------------- Sobel edge fraction -------------
    int ec = 0;
#pragma unroll 4
    for (int k = 0; k < 16; ++k) {
      int p = k * 256 + tid;
      int r = p >> 6, c = p & 63;
      float P[3][3];
#pragma unroll
      for (int i = 0; i < 3; ++i)
#pragma unroll
        for (int j = 0; j < 3; ++j) {
          int rr = min(max(r + i - 1, 0), 63);
          int cc = min(max(c + j - 1, 0), 63);
          P[i][j] = sp[rr * 65 + cc];
        }
      float gx = (P[0][2] - P[0][0]) + 2.f * (P[1][2] - P[1][0]) + (P[2][2] - P[2][0]);
      float gy = (P[2][0] - P[0][0]) + 2.f * (P[2][1] - P[0][1]) + (P[2][2] - P[0][2]);
      if (gx * gx + gy * gy > 0.01f) ++ec;
    }
    float E = block_reduce((float)ec, red);
    if (tid == 0) emit(out, b, 8, E * (1.f / 4096.f));  // edge
  } else {
    // ------------- Gabor: ONE separable component per block -------------
    const int comp = type - 4;
    const int sf = comp >> 2, u = comp & 3;
    float* H1 = sm + 4160;
    float s1 = 0.f, s2 = 0.f;
    if (sf < 2) {
      hpass<3>(sp, H1, prof, tid); __syncthreads();
      vpass1<3>(H1, prof + 19, tid, s1, s2);
    } else if (u < 2) {
      hpass<9>(sp, H1, prof, tid); __syncthreads();
      vpass1<9>(H1, prof + 19, tid, s1, s2);
    } else {
      hpass<7>(sp, H1, prof, tid); __syncthreads();
      vpass1<7>(H1, prof + 19, tid, s1, s2);
    }
    float S1 = block_reduce(s1, red), S2 = block_reduce(s2, red);
    if (tid == 0) {
      const float inv = 1.f / 4096.f;
      float var = S2 * inv - (S1 * inv) * (S1 * inv);
      float wgt = (u < 2) ? 1.f : 2.f;   // diag pair: var sum = 2var(cc)+2var(ss)
      atomicAdd((float*)(ws + WS_ETEX + b), wgt * var * (1.f / 1600.f));
    }
  }
}

// =======================================================================
// Kernel C: finalize etex (feat 7) after all gabor blocks accumulated.
// =======================================================================
__global__ void __launch_bounds__(256)
mfeC(const float* __restrict__ ws, float* __restrict__ out) {
  int b = threadIdx.x;
  emit(out, b, 7, ws[WS_ETEX + b]);
}

extern "C" void kernel_launch(void* const* d_in, const int* in_sizes, int n_in,
                              void* d_out, int out_size, void* d_ws, size_t ws_size,
                              hipStream_t stream) {
  (void)in_sizes; (void)n_in; (void)out_size;
  // Needs ~10.6 MB scratch; bail cleanly (clean failed-verify) if undersized.
  if (ws_size < (size_t)WS_TOTAL * sizeof(float)) return;
  const float* x = (const float*)d_in[0];
  float* out = (float*)d_out;
  float* ws = (float*)d_ws;
  // zero only the atomic-accumulated regions (MS, SCAL, ETEX) — 54 KB
  hipMemsetAsync((char*)d_ws + (size_t)WS_MS * 4, 0,
                 (size_t)(WS_TOTAL - WS_MS) * 4, stream);
  hipLaunchKernelGGL(mfeA, dim3(1024), dim3(256), 0, stream, x, ws);
  hipLaunchKernelGGL(mfeB, dim3(256, 20), dim3(256), 0, stream, ws, out);
  hipLaunchKernelGGL(mfeC, dim3(1), dim3(256), 0, stream, ws, out);
}